// Round 12
// baseline (28.881 us; speedup 1.0000x reference)
//
#include <hip/hip_runtime.h>

#define BATCH 262144
#define NUM_LAYERS 64

typedef float f32x2 __attribute__((ext_vector_type(2)));
typedef float f32x4 __attribute__((ext_vector_type(4)));

// R7 structure (best: 26.8us), parameterized by a pair-range base so the same
// total work can be enqueued as TWO half-batch launches. This is a controlled
// probe for fixed per-launch overhead: identical total device work, 2x the
// launch count. p0 = starting pair index; each thread handles pairs (2g,2g+1).
template <int MODE>
__global__ __launch_bounds__(256) void squbit_kernel(
    const float* __restrict__ X,       // (BATCH, 2)
    const float* __restrict__ W,       // (NUM_LAYERS, 3)
    const float* __restrict__ Bi,      // (NUM_LAYERS, 3)
    float* __restrict__ out,
    int p0)
{
    __shared__ float4 cA[NUM_LAYERS];   // {0.5*w0, 0.5*b0 + hom_prev, 0.5*w1, 0.5*b1}
    __shared__ float2 cOm[NUM_LAYERS];  // {cos(om/2), sin(om/2)}

    const int t = threadIdx.x;
    if (t < NUM_LAYERS) {
        const float w0 = W[t * 3 + 0], w1 = W[t * 3 + 1], w2 = W[t * 3 + 2];
        const float b0 = Bi[t * 3 + 0], b1 = Bi[t * 3 + 1], b2 = Bi[t * 3 + 2];
        float hom_prev = 0.0f;
        if (t > 0) hom_prev = 0.5f * (W[(t - 1) * 3 + 2] + Bi[(t - 1) * 3 + 2]);
        cA[t] = make_float4(0.5f * w0, fmaf(0.5f, b0, hom_prev), 0.5f * w1, 0.5f * b1);
        const float hom = 0.5f * (w2 + b2);
        float so, co;
        __sincosf(hom, &so, &co);
        cOm[t] = make_float2(co, so);
    }
    __syncthreads();

    const int g = p0 + blockIdx.x * 256 + t;     // pair index: elems 2g, 2g+1
    const float4 xx = reinterpret_cast<const float4*>(X)[g];

    const f32x2 x0 = {xx.x, xx.z};   // X[:,0] for A,B
    const f32x2 x1 = {xx.y, xx.w};   // X[:,1] for A,B

    // pre-omega state, lanes = (A,B)
    f32x2 ur0 = {1.0f, 1.0f}, ui0 = {0.0f, 0.0f};
    f32x2 ur1 = {0.0f, 0.0f}, ui1 = {0.0f, 0.0f};

    f32x4* o4 = reinterpret_cast<f32x4*>(out);

    #pragma unroll 4
    for (int l = 0; l < NUM_LAYERS; ++l) {
        const float4 c = cA[l];
        const float2 om = cOm[l];

        const f32x2 hpsiV = x0 * c.x + c.y;
        const f32x2 hthV  = x1 * c.z + c.w;

        float s0, c0, s1, c1, s2, c2, s3, c3;
        __sincosf(hpsiV.x, &s0, &c0);
        __sincosf(hpsiV.y, &s1, &c1);
        __sincosf(hthV.x,  &s2, &c2);
        __sincosf(hthV.y,  &s3, &c3);
        const f32x2 sps = {s0, s1}, cps = {c0, c1};
        const f32x2 sth = {s2, s3}, cth = {c2, c3};

        // Rz(psi): a0 = u0 * (cps - i*sps); a1 = u1 * (cps + i*sps)
        const f32x2 a0r = ui0 * sps + ur0 * cps;
        const f32x2 a0i = ui0 * cps - ur0 * sps;
        const f32x2 a1r = ur1 * cps - ui1 * sps;
        const f32x2 a1i = ui1 * cps + ur1 * sps;
        // Ry(th)
        ur0 = cth * a0r - sth * a1r;
        ui0 = cth * a0i - sth * a1i;
        ur1 = sth * a0r + cth * a1r;
        ui1 = sth * a0i + cth * a1i;

        // store-side Rz(omega): t0 = u0*(co - i so), t1 = u1*(co + i so)
        if (MODE == 0) {
            const f32x2 t0r = ui0 * om.y + ur0 * om.x;
            const f32x2 t1r = ur1 * om.x - ui1 * om.y;
            f32x4 v; v.x = t0r.x; v.y = t1r.x; v.z = t0r.y; v.w = t1r.y;
            o4[l * (BATCH / 2) + g] = v;
        } else {
            const f32x2 t0r = ui0 * om.y + ur0 * om.x;
            const f32x2 t0i = ui0 * om.x - ur0 * om.y;
            const f32x2 t1r = ur1 * om.x - ui1 * om.y;
            const f32x2 t1i = ui1 * om.x + ur1 * om.y;
            f32x4 va; va.x = t0r.x; va.y = t0i.x; va.z = t1r.x; va.w = t1i.x;
            f32x4 vb; vb.x = t0r.y; vb.y = t0i.y; vb.z = t1r.y; vb.w = t1i.y;
            o4[(l * BATCH + 2 * g) + 0] = va;
            o4[(l * BATCH + 2 * g) + 1] = vb;
        }
    }
}

extern "C" void kernel_launch(void* const* d_in, const int* in_sizes, int n_in,
                              void* d_out, int out_size, void* d_ws, size_t ws_size,
                              hipStream_t stream) {
    const float* X  = (const float*)d_in[0];
    const float* W  = (const float*)d_in[1];
    const float* Bi = (const float*)d_in[2];
    float* out = (float*)d_out;

    const int PAIRS = BATCH / 2;           // 131072
    const int HALF  = PAIRS / 2;           // 65536 pairs per launch
    dim3 grid(HALF / 256), block(256);     // 256 blocks per launch

    const long long full_complex_floats = (long long)NUM_LAYERS * BATCH * 4;
    if ((long long)out_size >= full_complex_floats) {
        squbit_kernel<1><<<grid, block, 0, stream>>>(X, W, Bi, out, 0);
        squbit_kernel<1><<<grid, block, 0, stream>>>(X, W, Bi, out, HALF);
    } else {
        squbit_kernel<0><<<grid, block, 0, stream>>>(X, W, Bi, out, 0);
        squbit_kernel<0><<<grid, block, 0, stream>>>(X, W, Bi, out, HALF);
    }
}